// Round 1
// baseline (186.858 us; speedup 1.0000x reference)
//
#include <hip/hip_runtime.h>

typedef __attribute__((ext_vector_type(8))) short bf16x8;
typedef __attribute__((ext_vector_type(4))) float f32x4;
typedef __attribute__((ext_vector_type(4))) unsigned short u16x4;

#define MFMA16(a, b, c) __builtin_amdgcn_mfma_f32_16x16x32_bf16(a, b, c, 0, 0, 0)

// B=16, S=2048, EMB=512, HEAD_DIM=64

__device__ __forceinline__ unsigned short f2bf(float f) {
    union { float f; unsigned int u; } v; v.f = f;
    unsigned int r = v.u + 0x7FFFu + ((v.u >> 16) & 1u);
    return (unsigned short)(r >> 16);
}

// Wt[mat][h][e] = bf16(W_mat[e][h])  -- transposed so MFMA B-fragments are contiguous in e
__global__ void wt_kernel(const float* __restrict__ Wq, const float* __restrict__ Wk,
                          const float* __restrict__ Wv, unsigned short* __restrict__ Wt) {
    const int h = blockIdx.x;      // 0..63
    const int mat = blockIdx.y;    // 0..2
    const int e = threadIdx.x;     // 0..511
    const float* W = (mat == 0) ? Wq : ((mat == 1) ? Wk : Wv);
    Wt[(mat * 64 + h) * 512 + e] = f2bf(W[e * 64 + h]);
}

// Fused QKV projection. Each wave computes 16 tokens x (q|k|v 64 cols each).
// A = x1 rows (fp32 -> bf16 inline), B = Wt rows. acc fp32.
// Q stored row-major bf16 *0.125 (exact pow2, folds softmax scale).
// K stored row-major bf16. V stored TRANSPOSED: Vt[b][d=64][s=2048].
__global__ __launch_bounds__(256) void qkv_proj(
    const float* __restrict__ x1, const unsigned short* __restrict__ Wt,
    unsigned short* __restrict__ Q, unsigned short* __restrict__ K,
    unsigned short* __restrict__ Vt)
{
    const int w = threadIdx.x >> 6;
    const int lane = threadIdx.x & 63;
    const int c = lane & 15, g = lane >> 4;
    const int tok0 = blockIdx.x * 64 + w * 16;

    f32x4 acc[12];
#pragma unroll
    for (int n = 0; n < 12; ++n) acc[n] = (f32x4)0.f;

    const float* arow = x1 + (size_t)(tok0 + c) * 512;

#pragma unroll 2
    for (int ks = 0; ks < 16; ++ks) {
        const int e0 = ks * 32 + g * 8;
        f32x4 a0 = *(const f32x4*)(arow + e0);
        f32x4 a1 = *(const f32x4*)(arow + e0 + 4);
        bf16x8 af;
        af[0] = (short)f2bf(a0[0]); af[1] = (short)f2bf(a0[1]);
        af[2] = (short)f2bf(a0[2]); af[3] = (short)f2bf(a0[3]);
        af[4] = (short)f2bf(a1[0]); af[5] = (short)f2bf(a1[1]);
        af[6] = (short)f2bf(a1[2]); af[7] = (short)f2bf(a1[3]);
        const unsigned short* bbase = Wt + e0;
#pragma unroll
        for (int n = 0; n < 12; ++n) {
            const int mat = n >> 2;
            const int hh = (n & 3) * 16 + c;
            bf16x8 bf = *(const bf16x8*)(bbase + (mat * 64 + hh) * 512);
            acc[n] = MFMA16(af, bf, acc[n]);
        }
    }

    // D-layout: col = lane&15 (output dim), row = g*4+r (token)
#pragma unroll
    for (int n = 0; n < 4; ++n)
#pragma unroll
        for (int r = 0; r < 4; ++r)
            Q[(size_t)(tok0 + g * 4 + r) * 64 + n * 16 + c] = f2bf(acc[n][r] * 0.125f);
#pragma unroll
    for (int n = 0; n < 4; ++n)
#pragma unroll
        for (int r = 0; r < 4; ++r)
            K[(size_t)(tok0 + g * 4 + r) * 64 + n * 16 + c] = f2bf(acc[4 + n][r]);

    const int b = tok0 >> 11;             // batch
    const int sl = (tok0 & 2047) + g * 4; // seq pos within batch
#pragma unroll
    for (int n = 0; n < 4; ++n) {
        const int d = n * 16 + c;
        u16x4 pv;
#pragma unroll
        for (int r = 0; r < 4; ++r) pv[r] = f2bf(acc[8 + n][r]);
        *(u16x4*)(Vt + ((size_t)(b * 64 + d) << 11) + sl) = pv;  // 4 consecutive tokens -> 8B write
    }
}

// Causal flash attention. 4 waves x 16 q-rows per block (QBLK=64), KBLK=64.
// K/V fragments read directly from global (per-batch K/V = 256KB -> L2-resident;
// LDS staging would be pure overhead). LDS used only for per-wave P transpose.
__global__ __launch_bounds__(256) void flash_attn(
    const unsigned short* __restrict__ Q, const unsigned short* __restrict__ K,
    const unsigned short* __restrict__ Vt, float* __restrict__ out)
{
    __shared__ unsigned short p_lds[4][16][72];  // per-wave, padded (+8) rows
    const int w = threadIdx.x >> 6;
    const int lane = threadIdx.x & 63;
    const int c = lane & 15, g = lane >> 4;
    const int qt = 31 - (int)blockIdx.x;   // big blocks dispatch first (tail balance)
    const int b = blockIdx.y;
    const int qr0 = qt * 64 + w * 16;                 // q-row base within batch
    const size_t qrow_g = ((size_t)b << 11) + qr0;    // global token row

    // Q A-fragments: row = c, k(d) = kh*32 + g*8 .. +8 (Q pre-scaled by 0.125)
    bf16x8 qf0 = *(const bf16x8*)(Q + (qrow_g + c) * 64 + g * 8);
    bf16x8 qf1 = *(const bf16x8*)(Q + (qrow_g + c) * 64 + 32 + g * 8);

    const unsigned short* Kb = K + (size_t)b * 2048 * 64;
    const unsigned short* Vb = Vt + (size_t)b * 64 * 2048;  // [d][s]

    float m_run[4], l_run[4];
    f32x4 acc_o[4];
#pragma unroll
    for (int r = 0; r < 4; ++r) { m_run[r] = -1e30f; l_run[r] = 0.f; }
#pragma unroll
    for (int n = 0; n < 4; ++n) acc_o[n] = (f32x4)0.f;

    for (int kt = 0; kt <= qt; ++kt) {
        // ---- S = Q K^T (pre-scaled). D-layout: col=key c, rows=g*4+r ----
        f32x4 s[4];
#pragma unroll
        for (int n = 0; n < 4; ++n) s[n] = (f32x4)0.f;
#pragma unroll
        for (int n = 0; n < 4; ++n) {
            const unsigned short* kp = Kb + (size_t)(kt * 64 + n * 16 + c) * 64 + g * 8;
            bf16x8 k0 = *(const bf16x8*)kp;
            bf16x8 k1 = *(const bf16x8*)(kp + 32);
            s[n] = MFMA16(qf0, k0, s[n]);
            s[n] = MFMA16(qf1, k1, s[n]);
        }
        // ---- causal mask (diagonal tile only) ----
        if (kt == qt) {
#pragma unroll
            for (int n = 0; n < 4; ++n) {
                const int key = kt * 64 + n * 16 + c;
#pragma unroll
                for (int r = 0; r < 4; ++r)
                    if (key > qr0 + g * 4 + r) s[n][r] = -1e30f;
            }
        }
        // ---- online softmax: row stats live in the 16-lane group sharing g ----
        float tm[4];
#pragma unroll
        for (int r = 0; r < 4; ++r)
            tm[r] = fmaxf(fmaxf(s[0][r], s[1][r]), fmaxf(s[2][r], s[3][r]));
#pragma unroll
        for (int off = 1; off < 16; off <<= 1)
#pragma unroll
            for (int r = 0; r < 4; ++r)
                tm[r] = fmaxf(tm[r], __shfl_xor(tm[r], off, 64));

        float alpha[4], rs[4];
#pragma unroll
        for (int r = 0; r < 4; ++r) {
            const float mn = fmaxf(m_run[r], tm[r]);
            alpha[r] = __expf(m_run[r] - mn);
            m_run[r] = mn;
            rs[r] = 0.f;
        }
#pragma unroll
        for (int n = 0; n < 4; ++n)
#pragma unroll
            for (int r = 0; r < 4; ++r) {
                const float p = __expf(s[n][r] - m_run[r]);
                rs[r] += p;
                p_lds[w][g * 4 + r][n * 16 + c] = f2bf(p);  // transpose P via LDS
            }
#pragma unroll
        for (int off = 1; off < 16; off <<= 1)
#pragma unroll
            for (int r = 0; r < 4; ++r)
                rs[r] += __shfl_xor(rs[r], off, 64);
#pragma unroll
        for (int r = 0; r < 4; ++r) l_run[r] = l_run[r] * alpha[r] + rs[r];
#pragma unroll
        for (int n = 0; n < 4; ++n)
#pragma unroll
            for (int r = 0; r < 4; ++r) acc_o[n][r] *= alpha[r];

        // ---- O += P V : A = P (from LDS), B = V from Vt[d][s] (contiguous in s) ----
        bf16x8 pf0 = *(const bf16x8*)&p_lds[w][c][g * 8];
        bf16x8 pf1 = *(const bf16x8*)&p_lds[w][c][32 + g * 8];
#pragma unroll
        for (int n = 0; n < 4; ++n) {
            const unsigned short* vp = Vb + (size_t)(n * 16 + c) * 2048 + kt * 64 + g * 8;
            bf16x8 v0 = *(const bf16x8*)vp;
            bf16x8 v1 = *(const bf16x8*)(vp + 32);
            acc_o[n] = MFMA16(pf0, v0, acc_o[n]);
            acc_o[n] = MFMA16(pf1, v1, acc_o[n]);
        }
    }

    float inv_l[4];
#pragma unroll
    for (int r = 0; r < 4; ++r) inv_l[r] = 1.f / l_run[r];
#pragma unroll
    for (int n = 0; n < 4; ++n)
#pragma unroll
        for (int r = 0; r < 4; ++r)
            out[(qrow_g + g * 4 + r) * 64 + n * 16 + c] = acc_o[n][r] * inv_l[r];
}

extern "C" void kernel_launch(void* const* d_in, const int* in_sizes, int n_in,
                              void* d_out, int out_size, void* d_ws, size_t ws_size,
                              hipStream_t stream) {
    const float* x1 = (const float*)d_in[0];
    // d_in[1] = mask: tril by construction -> handled analytically
    const float* Wq = (const float*)d_in[2];
    const float* Wk = (const float*)d_in[3];
    const float* Wv = (const float*)d_in[4];
    float* out = (float*)d_out;

    // ws layout (needs ~12.8 MB):
    //   Wt  [3][64][512] bf16 : 196608 B
    //   Q   [32768][64]  bf16 : 4 MiB (pre-scaled by 0.125)
    //   K   [32768][64]  bf16 : 4 MiB
    //   Vt  [16][64][2048] bf16 : 4 MiB (per-batch transposed V)
    unsigned short* Wt  = (unsigned short*)d_ws;
    unsigned short* Qw  = (unsigned short*)((char*)d_ws + 196608);
    unsigned short* Kw  = (unsigned short*)((char*)d_ws + 196608 + 4194304);
    unsigned short* Vtw = (unsigned short*)((char*)d_ws + 196608 + 2 * 4194304);

    wt_kernel<<<dim3(64, 3), 512, 0, stream>>>(Wq, Wk, Wv, Wt);
    qkv_proj<<<512, 256, 0, stream>>>(x1, Wt, Qw, Kw, Vtw);
    flash_attn<<<dim3(32, 16), 256, 0, stream>>>(Qw, Kw, Vtw, out);
}

// Round 2
// 133.462 us; speedup vs baseline: 1.4001x; 1.4001x over previous
//
#include <hip/hip_runtime.h>

typedef __attribute__((ext_vector_type(8))) short bf16x8;
typedef __attribute__((ext_vector_type(4))) float f32x4;
typedef __attribute__((ext_vector_type(4))) unsigned short u16x4;

#define MFMA16(a, b, c) __builtin_amdgcn_mfma_f32_16x16x32_bf16(a, b, c, 0, 0, 0)

// B=16, S=2048, EMB=512, HEAD_DIM=64
// Q is pre-scaled by 0.125 * log2(e) so softmax runs in exp2 domain.
#define QSCALE 0.18033688011112042f

__device__ __forceinline__ unsigned short f2bf(float f) {
    union { float f; unsigned int u; } v; v.f = f;
    unsigned int r = v.u + 0x7FFFu + ((v.u >> 16) & 1u);
    return (unsigned short)(r >> 16);
}

// Wt[mat][h][e] = bf16(W_mat[e][h])
__global__ void wt_kernel(const float* __restrict__ Wq, const float* __restrict__ Wk,
                          const float* __restrict__ Wv, unsigned short* __restrict__ Wt) {
    const int h = blockIdx.x;      // 0..63
    const int mat = blockIdx.y;    // 0..2
    const int e = threadIdx.x;     // 0..511
    const float* W = (mat == 0) ? Wq : ((mat == 1) ? Wk : Wv);
    Wt[(mat * 64 + h) * 512 + e] = f2bf(W[e * 64 + h]);
}

// Fused QKV projection (unchanged structure; Q scale now 0.125*log2e).
__global__ __launch_bounds__(256) void qkv_proj(
    const float* __restrict__ x1, const unsigned short* __restrict__ Wt,
    unsigned short* __restrict__ Q, unsigned short* __restrict__ K,
    unsigned short* __restrict__ Vt)
{
    const int w = threadIdx.x >> 6;
    const int lane = threadIdx.x & 63;
    const int c = lane & 15, g = lane >> 4;
    const int tok0 = blockIdx.x * 64 + w * 16;

    f32x4 acc[12];
#pragma unroll
    for (int n = 0; n < 12; ++n) acc[n] = (f32x4)0.f;

    const float* arow = x1 + (size_t)(tok0 + c) * 512;

#pragma unroll 2
    for (int ks = 0; ks < 16; ++ks) {
        const int e0 = ks * 32 + g * 8;
        f32x4 a0 = *(const f32x4*)(arow + e0);
        f32x4 a1 = *(const f32x4*)(arow + e0 + 4);
        bf16x8 af;
        af[0] = (short)f2bf(a0[0]); af[1] = (short)f2bf(a0[1]);
        af[2] = (short)f2bf(a0[2]); af[3] = (short)f2bf(a0[3]);
        af[4] = (short)f2bf(a1[0]); af[5] = (short)f2bf(a1[1]);
        af[6] = (short)f2bf(a1[2]); af[7] = (short)f2bf(a1[3]);
        const unsigned short* bbase = Wt + e0;
#pragma unroll
        for (int n = 0; n < 12; ++n) {
            const int mat = n >> 2;
            const int hh = (n & 3) * 16 + c;
            bf16x8 bf = *(const bf16x8*)(bbase + (mat * 64 + hh) * 512);
            acc[n] = MFMA16(af, bf, acc[n]);
        }
    }

#pragma unroll
    for (int n = 0; n < 4; ++n)
#pragma unroll
        for (int r = 0; r < 4; ++r)
            Q[(size_t)(tok0 + g * 4 + r) * 64 + n * 16 + c] = f2bf(acc[n][r] * QSCALE);
#pragma unroll
    for (int n = 0; n < 4; ++n)
#pragma unroll
        for (int r = 0; r < 4; ++r)
            K[(size_t)(tok0 + g * 4 + r) * 64 + n * 16 + c] = f2bf(acc[4 + n][r]);

    const int b = tok0 >> 11;
    const int sl = (tok0 & 2047) + g * 4;
#pragma unroll
    for (int n = 0; n < 4; ++n) {
        const int d = n * 16 + c;
        u16x4 pv;
#pragma unroll
        for (int r = 0; r < 4; ++r) pv[r] = f2bf(acc[8 + n][r]);
        *(u16x4*)(Vt + ((size_t)(b * 64 + d) << 11) + sl) = pv;
    }
}

// Causal flash attention v2.
//  - 1-D grid of 512 blocks; swizzle: XCD = id&7 owns batches {2*xcd, 2*xcd+1}
//    (per-XCD K/V working set = 1MB -> L2 resident), and CU pair (id, id+256)
//    gets complementary qt (sum=31) -> uniform 33 iters per CU.
//  - Swapped QK^T: s = mfma(K, Q) -> lane holds S[key][q=c]; softmax reduce is
//    2 shfls (xor16, xor32) instead of 4-step chains; m/l are scalar per lane.
//  - exp2-domain softmax, defer-max (THR=8), explicit K-next/V prefetch regs,
//    setprio around MFMA clusters.
__global__ __launch_bounds__(256, 1) void flash_attn(
    const unsigned short* __restrict__ Q, const unsigned short* __restrict__ K,
    const unsigned short* __restrict__ Vt, float* __restrict__ out)
{
    __shared__ unsigned short p_lds[4][16][72];
    const int w = threadIdx.x >> 6;
    const int lane = threadIdx.x & 63;
    const int c = lane & 15, g = lane >> 4;

    const int id = blockIdx.x;            // 0..511
    const int xcd = id & 7;
    const int b = 2 * xcd + ((id >> 3) & 1);
    const int bxx = id >> 4;              // 0..31
    const int qt = (bxx < 16) ? bxx : 47 - bxx;   // pair (bxx, bxx+16): qt sum = 31

    const int qr0 = qt * 64 + w * 16;
    const size_t qrow_g = ((size_t)b << 11) + qr0;

    // Q fragments (B operand): lane (c,g) = Q[q=c][d=g*8..]
    bf16x8 qf0 = *(const bf16x8*)(Q + (qrow_g + c) * 64 + g * 8);
    bf16x8 qf1 = *(const bf16x8*)(Q + (qrow_g + c) * 64 + 32 + g * 8);

    const unsigned short* Kb = K + (((size_t)b << 11) * 64);
    const unsigned short* Vb = Vt + (((size_t)b << 11) * 64);  // [d=64][s=2048]

    float m_run = -1e30f, l_run = 0.f;
    f32x4 acc_o[4];
#pragma unroll
    for (int n = 0; n < 4; ++n) acc_o[n] = (f32x4)0.f;

    // preload K tile 0 (A operand): lane (c,g) = K[key=n*16+c][d=g*8..]
    bf16x8 kf[8];
#pragma unroll
    for (int n = 0; n < 4; ++n) {
        const unsigned short* kp = Kb + (size_t)(n * 16 + c) * 64 + g * 8;
        kf[2 * n]     = *(const bf16x8*)kp;
        kf[2 * n + 1] = *(const bf16x8*)(kp + 32);
    }

    for (int kt = 0; kt <= qt; ++kt) {
        // ---- S^T = K Q^T : lane (c,g) reg r = S[key=kt*64+n*16+g*4+r][q=c] ----
        f32x4 s[4];
#pragma unroll
        for (int n = 0; n < 4; ++n) s[n] = (f32x4)0.f;
        __builtin_amdgcn_s_setprio(1);
#pragma unroll
        for (int n = 0; n < 4; ++n) {
            s[n] = MFMA16(kf[2 * n], qf0, s[n]);
            s[n] = MFMA16(kf[2 * n + 1], qf1, s[n]);
        }
        __builtin_amdgcn_s_setprio(0);

        // ---- prefetch: V for this tile, K for next tile ----
        bf16x8 vf[8];
#pragma unroll
        for (int n = 0; n < 4; ++n) {
            const unsigned short* vp = Vb + (size_t)(n * 16 + c) * 2048 + kt * 64 + g * 8;
            vf[2 * n]     = *(const bf16x8*)vp;
            vf[2 * n + 1] = *(const bf16x8*)(vp + 32);
        }
        const int ktn = (kt < qt) ? kt + 1 : qt;
        bf16x8 knf[8];
#pragma unroll
        for (int n = 0; n < 4; ++n) {
            const unsigned short* kp = Kb + (size_t)(ktn * 64 + n * 16 + c) * 64 + g * 8;
            knf[2 * n]     = *(const bf16x8*)kp;
            knf[2 * n + 1] = *(const bf16x8*)(kp + 32);
        }

        // ---- causal mask (diagonal tile only) ----
        if (kt == qt) {
#pragma unroll
            for (int n = 0; n < 4; ++n) {
                const int key = kt * 64 + n * 16 + g * 4;
#pragma unroll
                for (int r = 0; r < 4; ++r)
                    if (key + r > qr0 + c) s[n][r] = -1e30f;
            }
        }

        // ---- online softmax (exp2 domain), per-lane scalar state for q=c ----
        float tm = s[0][0];
#pragma unroll
        for (int n = 0; n < 4; ++n)
#pragma unroll
            for (int r = 0; r < 4; ++r) tm = fmaxf(tm, s[n][r]);
        tm = fmaxf(tm, __shfl_xor(tm, 16, 64));
        tm = fmaxf(tm, __shfl_xor(tm, 32, 64));

        if (__any(tm > m_run + 8.f)) {      // defer-max: rescale only on real growth
            const float mn = fmaxf(m_run, tm);
            const float alpha = exp2f(m_run - mn);
            m_run = mn;
            l_run *= alpha;
            float al[4];
#pragma unroll
            for (int r = 0; r < 4; ++r) al[r] = __shfl(alpha, g * 4 + r, 16);
#pragma unroll
            for (int n = 0; n < 4; ++n)
#pragma unroll
                for (int r = 0; r < 4; ++r) acc_o[n][r] *= al[r];
        }

        float rs = 0.f;
#pragma unroll
        for (int n = 0; n < 4; ++n) {
            u16x4 pk;
#pragma unroll
            for (int r = 0; r < 4; ++r) {
                const float p = exp2f(s[n][r] - m_run);
                rs += p;
                pk[r] = f2bf(p);
            }
            *(u16x4*)&p_lds[w][c][n * 16 + g * 4] = pk;  // P[q=c][key n*16+g*4..+3]
        }
        rs += __shfl_xor(rs, 16, 64);
        rs += __shfl_xor(rs, 32, 64);
        l_run += rs;

        // ---- O += P V ----
        bf16x8 pf0 = *(const bf16x8*)&p_lds[w][c][g * 8];
        bf16x8 pf1 = *(const bf16x8*)&p_lds[w][c][32 + g * 8];
        __builtin_amdgcn_s_setprio(1);
#pragma unroll
        for (int n = 0; n < 4; ++n) {
            acc_o[n] = MFMA16(pf0, vf[2 * n], acc_o[n]);
            acc_o[n] = MFMA16(pf1, vf[2 * n + 1], acc_o[n]);
        }
        __builtin_amdgcn_s_setprio(0);

#pragma unroll
        for (int i = 0; i < 8; ++i) kf[i] = knf[i];
    }

    const float inv_l = 1.f / l_run;
    float il[4];
#pragma unroll
    for (int r = 0; r < 4; ++r) il[r] = __shfl(inv_l, g * 4 + r, 16);
#pragma unroll
    for (int n = 0; n < 4; ++n)
#pragma unroll
        for (int r = 0; r < 4; ++r)
            out[(qrow_g + g * 4 + r) * 64 + n * 16 + c] = acc_o[n][r] * il[r];
}

extern "C" void kernel_launch(void* const* d_in, const int* in_sizes, int n_in,
                              void* d_out, int out_size, void* d_ws, size_t ws_size,
                              hipStream_t stream) {
    const float* x1 = (const float*)d_in[0];
    const float* Wq = (const float*)d_in[2];
    const float* Wk = (const float*)d_in[3];
    const float* Wv = (const float*)d_in[4];
    float* out = (float*)d_out;

    unsigned short* Wt  = (unsigned short*)d_ws;
    unsigned short* Qw  = (unsigned short*)((char*)d_ws + 196608);
    unsigned short* Kw  = (unsigned short*)((char*)d_ws + 196608 + 4194304);
    unsigned short* Vtw = (unsigned short*)((char*)d_ws + 196608 + 2 * 4194304);

    wt_kernel<<<dim3(64, 3), 512, 0, stream>>>(Wq, Wk, Wv, Wt);
    qkv_proj<<<512, 256, 0, stream>>>(x1, Wt, Qw, Kw, Vtw);
    flash_attn<<<512, 256, 0, stream>>>(Qw, Kw, Vtw, out);
}

// Round 3
// 108.657 us; speedup vs baseline: 1.7197x; 1.2283x over previous
//
#include <hip/hip_runtime.h>

typedef __attribute__((ext_vector_type(8))) short bf16x8;
typedef __attribute__((ext_vector_type(4))) float f32x4;
typedef __attribute__((ext_vector_type(4))) unsigned short u16x4;

#define MFMA16(a, b, c) __builtin_amdgcn_mfma_f32_16x16x32_bf16(a, b, c, 0, 0, 0)

// B=16, S=2048, EMB=512, HEAD_DIM=64
// Q pre-scaled by 0.125 * log2(e): softmax runs in exp2 domain.
#define QSCALE 0.18033688011112042f

#define GLDS16(gp, lp)                                                         \
    __builtin_amdgcn_global_load_lds(                                          \
        (const __attribute__((address_space(1))) void*)(gp),                   \
        (__attribute__((address_space(3))) void*)(lp), 16, 0, 0)

__device__ __forceinline__ unsigned short f2bf(float f) {
    union { float f; unsigned int u; } v; v.f = f;
    unsigned int r = v.u + 0x7FFFu + ((v.u >> 16) & 1u);
    return (unsigned short)(r >> 16);
}

// Wt[mat][h][e] = bf16(W_mat[e][h])
__global__ void wt_kernel(const float* __restrict__ Wq, const float* __restrict__ Wk,
                          const float* __restrict__ Wv, unsigned short* __restrict__ Wt) {
    const int h = blockIdx.x;
    const int mat = blockIdx.y;
    const int e = threadIdx.x;
    const float* W = (mat == 0) ? Wq : ((mat == 1) ? Wk : Wv);
    Wt[(mat * 64 + h) * 512 + e] = f2bf(W[e * 64 + h]);
}

// Fused QKV projection with explicit software pipeline (prefetch next-k A & B
// into dedicated registers while MFMAs consume current ones).
__global__ __launch_bounds__(256, 1) void qkv_proj(
    const float* __restrict__ x1, const unsigned short* __restrict__ Wt,
    unsigned short* __restrict__ Q, unsigned short* __restrict__ K,
    unsigned short* __restrict__ Vt)
{
    const int w = threadIdx.x >> 6;
    const int lane = threadIdx.x & 63;
    const int c = lane & 15, g = lane >> 4;
    const int tok0 = blockIdx.x * 64 + w * 16;

    f32x4 acc[12];
#pragma unroll
    for (int n = 0; n < 12; ++n) acc[n] = (f32x4)0.f;

    const float* arow = x1 + (size_t)(tok0 + c) * 512;
    const unsigned short* bptr[12];
#pragma unroll
    for (int n = 0; n < 12; ++n)
        bptr[n] = Wt + (size_t)((n >> 2) * 64 + (n & 3) * 16 + c) * 512;

    // prologue: k-step 0
    f32x4 a0c = *(const f32x4*)(arow + g * 8);
    f32x4 a1c = *(const f32x4*)(arow + g * 8 + 4);
    bf16x8 bc[12];
#pragma unroll
    for (int n = 0; n < 12; ++n) bc[n] = *(const bf16x8*)(bptr[n] + g * 8);

#pragma unroll
    for (int ks = 0; ks < 16; ++ks) {
        f32x4 a0n, a1n;
        bf16x8 bn[12];
        if (ks < 15) {
            const int e1 = (ks + 1) * 32 + g * 8;
            a0n = *(const f32x4*)(arow + e1);
            a1n = *(const f32x4*)(arow + e1 + 4);
#pragma unroll
            for (int n = 0; n < 12; ++n) bn[n] = *(const bf16x8*)(bptr[n] + e1);
        }
        bf16x8 af;
        af[0] = (short)f2bf(a0c[0]); af[1] = (short)f2bf(a0c[1]);
        af[2] = (short)f2bf(a0c[2]); af[3] = (short)f2bf(a0c[3]);
        af[4] = (short)f2bf(a1c[0]); af[5] = (short)f2bf(a1c[1]);
        af[6] = (short)f2bf(a1c[2]); af[7] = (short)f2bf(a1c[3]);
#pragma unroll
        for (int n = 0; n < 12; ++n) acc[n] = MFMA16(af, bc[n], acc[n]);
        if (ks < 15) {
            a0c = a0n; a1c = a1n;
#pragma unroll
            for (int n = 0; n < 12; ++n) bc[n] = bn[n];
        }
    }

#pragma unroll
    for (int n = 0; n < 4; ++n)
#pragma unroll
        for (int r = 0; r < 4; ++r)
            Q[(size_t)(tok0 + g * 4 + r) * 64 + n * 16 + c] = f2bf(acc[n][r] * QSCALE);
#pragma unroll
    for (int n = 0; n < 4; ++n)
#pragma unroll
        for (int r = 0; r < 4; ++r)
            K[(size_t)(tok0 + g * 4 + r) * 64 + n * 16 + c] = f2bf(acc[4 + n][r]);

    const int b = tok0 >> 11;
    const int sl = (tok0 & 2047) + g * 4;
#pragma unroll
    for (int n = 0; n < 4; ++n) {
        const int d = n * 16 + c;
        u16x4 pv;
#pragma unroll
        for (int r = 0; r < 4; ++r) pv[r] = f2bf(acc[8 + n][r]);
        *(u16x4*)(Vt + ((size_t)(b * 64 + d) << 11) + sl) = pv;
    }
}

// Causal flash attention v3: cooperative async LDS staging of K/V tiles.
//  - double-buffered kv[2][16KB]; each wave issues 4 global_load_lds (w16)
//    per tile; raw s_barrier + manual vmcnt (NO __syncthreads -> no drain).
//  - XOR swizzle (byte ^= (row&7)<<4) on LDS reads; global SOURCE addresses
//    pre-swizzled so the linear global_load_lds dest yields swizzled layout.
//  - swapped QK^T (lane holds S[key][q=c]), exp2 softmax, defer-max.
__global__ __launch_bounds__(256, 1) void flash_attn(
    const unsigned short* __restrict__ Q, const unsigned short* __restrict__ K,
    const unsigned short* __restrict__ Vt, float* __restrict__ out)
{
    __shared__ unsigned short kv[2][8192];      // [buf][ K:0..4095 | V:4096..8191 ]
    __shared__ unsigned short p_lds[4][16][72];

    const int w = threadIdx.x >> 6;
    const int lane = threadIdx.x & 63;
    const int c = lane & 15, g = lane >> 4;

    const int id = blockIdx.x;
    const int xcd = id & 7;
    const int b = 2 * xcd + ((id >> 3) & 1);    // per-XCD batch pair -> L2-resident K/V
    const int bxx = id >> 4;
    const int qt = (bxx < 16) ? bxx : 47 - bxx; // CU pair (id,id+256): qt sum = 31
    const int qr0 = qt * 64 + w * 16;
    const size_t qrow_g = ((size_t)b << 11) + qr0;

    bf16x8 qf0 = *(const bf16x8*)(Q + (qrow_g + c) * 64 + g * 8);
    bf16x8 qf1 = *(const bf16x8*)(Q + (qrow_g + c) * 64 + 32 + g * 8);

    const char* Kb = (const char*)(K + (((size_t)b << 11) * 64));
    const char* Vb = (const char*)(Vt + (((size_t)b << 11) * 64));   // [d=64][s=2048]

    // staging: 8KB tile = 512 16B-chunks; wave w covers chunks [w*64,+64) and
    // [(w+4)*64,+64). chunk j -> row j>>3, col (j&7)*16; source pre-swizzled.
    const int j0 = w * 64 + lane;
    const int j1 = (w + 4) * 64 + lane;
    const int sw0 = (((j0 & 7) << 4) ^ (((j0 >> 3) & 7) << 4));
    const int sw1 = (((j1 & 7) << 4) ^ (((j1 >> 3) & 7) << 4));
    const int offk0 = (j0 >> 3) * 128 + sw0;
    const int offk1 = (j1 >> 3) * 128 + sw1;
    const int offv0 = (j0 >> 3) * 4096 + sw0;
    const int offv1 = (j1 >> 3) * 4096 + sw1;

    float m_run = -1e30f, l_run = 0.f;
    f32x4 acc_o[4];
#pragma unroll
    for (int n = 0; n < 4; ++n) acc_o[n] = (f32x4)0.f;

    int buf = 0;
    // prologue stage: tile 0 into buf 0
    {
        GLDS16(Kb + offk0, &kv[0][w * 512]);
        GLDS16(Kb + offk1, &kv[0][(w + 4) * 512]);
        GLDS16(Vb + offv0, &kv[0][4096 + w * 512]);
        GLDS16(Vb + offv1, &kv[0][4096 + (w + 4) * 512]);
    }

    const int sx = (c & 7) << 4;   // read-side swizzle for rows n*16+c

    for (int kt = 0; kt <= qt; ++kt) {
        // my stage for `buf` complete; everyone aligned -> safe to read buf
        asm volatile("s_waitcnt vmcnt(0)\n\ts_barrier" ::: "memory");

        // issue next tile stage into buf^1 (reads of buf^1 ended 2 barriers ago)
        if (kt < qt) {
            const size_t ko = (size_t)(kt + 1) * 8192;
            const size_t vo = (size_t)(kt + 1) * 128;
            GLDS16(Kb + ko + offk0, &kv[buf ^ 1][w * 512]);
            GLDS16(Kb + ko + offk1, &kv[buf ^ 1][(w + 4) * 512]);
            GLDS16(Vb + vo + offv0, &kv[buf ^ 1][4096 + w * 512]);
            GLDS16(Vb + vo + offv1, &kv[buf ^ 1][4096 + (w + 4) * 512]);
        }

        // ---- S^T = K Q^T from LDS (swizzled reads) ----
        const char* klc = (const char*)&kv[buf][0];
        f32x4 s[4];
#pragma unroll
        for (int n = 0; n < 4; ++n) s[n] = (f32x4)0.f;
        __builtin_amdgcn_s_setprio(1);
#pragma unroll
        for (int n = 0; n < 4; ++n) {
            const int ro = (n * 16 + c) * 128;
            bf16x8 ka = *(const bf16x8*)(klc + ro + ((g * 16) ^ sx));
            bf16x8 kb2 = *(const bf16x8*)(klc + ro + ((64 + g * 16) ^ sx));
            s[n] = MFMA16(ka, qf0, s[n]);
            s[n] = MFMA16(kb2, qf1, s[n]);
        }
        __builtin_amdgcn_s_setprio(0);

        // ---- causal mask (diagonal tile only) ----
        if (kt == qt) {
#pragma unroll
            for (int n = 0; n < 4; ++n) {
                const int key = kt * 64 + n * 16 + g * 4;
#pragma unroll
                for (int r = 0; r < 4; ++r)
                    if (key + r > qr0 + c) s[n][r] = -1e30f;
            }
        }

        // ---- online softmax (exp2 domain, defer-max THR=8) ----
        float tm = s[0][0];
#pragma unroll
        for (int n = 0; n < 4; ++n)
#pragma unroll
            for (int r = 0; r < 4; ++r) tm = fmaxf(tm, s[n][r]);
        tm = fmaxf(tm, __shfl_xor(tm, 16, 64));
        tm = fmaxf(tm, __shfl_xor(tm, 32, 64));

        if (__any(tm > m_run + 8.f)) {
            const float mn = fmaxf(m_run, tm);
            const float alpha = exp2f(m_run - mn);
            m_run = mn;
            l_run *= alpha;
            float al[4];
#pragma unroll
            for (int r = 0; r < 4; ++r) al[r] = __shfl(alpha, g * 4 + r, 16);
#pragma unroll
            for (int n = 0; n < 4; ++n)
#pragma unroll
                for (int r = 0; r < 4; ++r) acc_o[n][r] *= al[r];
        }

        float rs = 0.f;
#pragma unroll
        for (int n = 0; n < 4; ++n) {
            u16x4 pk;
#pragma unroll
            for (int r = 0; r < 4; ++r) {
                const float p = exp2f(s[n][r] - m_run);
                rs += p;
                pk[r] = f2bf(p);
            }
            *(u16x4*)&p_lds[w][c][n * 16 + g * 4] = pk;
        }
        rs += __shfl_xor(rs, 16, 64);
        rs += __shfl_xor(rs, 32, 64);
        l_run += rs;

        // ---- O += P V (V from LDS, swizzled) ----
        bf16x8 pf0 = *(const bf16x8*)&p_lds[w][c][g * 8];
        bf16x8 pf1 = *(const bf16x8*)&p_lds[w][c][32 + g * 8];
        const char* vlc = (const char*)&kv[buf][4096];
        __builtin_amdgcn_s_setprio(1);
#pragma unroll
        for (int n = 0; n < 4; ++n) {
            const int ro = (n * 16 + c) * 128;
            bf16x8 va = *(const bf16x8*)(vlc + ro + ((g * 16) ^ sx));
            bf16x8 vb2 = *(const bf16x8*)(vlc + ro + ((64 + g * 16) ^ sx));
            acc_o[n] = MFMA16(pf0, va, acc_o[n]);
            acc_o[n] = MFMA16(pf1, vb2, acc_o[n]);
        }
        __builtin_amdgcn_s_setprio(0);

        // all waves done reading buf before next iter overwrites it
        asm volatile("s_waitcnt lgkmcnt(0)\n\ts_barrier" ::: "memory");
        buf ^= 1;
    }

    const float inv_l = 1.f / l_run;
    float il[4];
#pragma unroll
    for (int r = 0; r < 4; ++r) il[r] = __shfl(inv_l, g * 4 + r, 16);
#pragma unroll
    for (int n = 0; n < 4; ++n)
#pragma unroll
        for (int r = 0; r < 4; ++r)
            out[(qrow_g + g * 4 + r) * 64 + n * 16 + c] = acc_o[n][r] * il[r];
}

extern "C" void kernel_launch(void* const* d_in, const int* in_sizes, int n_in,
                              void* d_out, int out_size, void* d_ws, size_t ws_size,
                              hipStream_t stream) {
    const float* x1 = (const float*)d_in[0];
    const float* Wq = (const float*)d_in[2];
    const float* Wk = (const float*)d_in[3];
    const float* Wv = (const float*)d_in[4];
    float* out = (float*)d_out;

    unsigned short* Wt  = (unsigned short*)d_ws;
    unsigned short* Qw  = (unsigned short*)((char*)d_ws + 196608);
    unsigned short* Kw  = (unsigned short*)((char*)d_ws + 196608 + 4194304);
    unsigned short* Vtw = (unsigned short*)((char*)d_ws + 196608 + 2 * 4194304);

    wt_kernel<<<dim3(64, 3), 512, 0, stream>>>(Wq, Wk, Wv, Wt);
    qkv_proj<<<512, 256, 0, stream>>>(x1, Wt, Qw, Kw, Vtw);
    flash_attn<<<512, 256, 0, stream>>>(Qw, Kw, Vtw, out);
}

// Round 4
// 74.604 us; speedup vs baseline: 2.5047x; 1.4565x over previous
//
#include <hip/hip_runtime.h>
#include <hip/hip_bf16.h>

typedef __attribute__((ext_vector_type(8))) short bf16x8;
typedef __attribute__((ext_vector_type(4))) float f32x4;
typedef __attribute__((ext_vector_type(4))) unsigned short u16x4;

#define MFMA16(a, b, c) __builtin_amdgcn_mfma_f32_16x16x32_bf16(a, b, c, 0, 0, 0)

// B=16, S=2048, EMB=512, HEAD_DIM=64
// Q pre-scaled by 0.125 * log2(e): softmax runs in exp2 domain.
#define QSCALE 0.18033688011112042f

#define GLDS16(gp, lp)                                                         \
    __builtin_amdgcn_global_load_lds(                                          \
        (const __attribute__((address_space(1))) void*)(gp),                   \
        (__attribute__((address_space(3))) void*)(lp), 16, 0, 0)

__device__ __forceinline__ short nbf(float f) {
    __hip_bfloat16 h = __float2bfloat16(f);
    return *(short*)&h;
}
__device__ __forceinline__ unsigned short nbfu(float f) {
    __hip_bfloat16 h = __float2bfloat16(f);
    return *(unsigned short*)&h;
}

// Wt[mat][h][e] = bf16(W_mat[e][h])
__global__ void wt_kernel(const float* __restrict__ Wq, const float* __restrict__ Wk,
                          const float* __restrict__ Wv, unsigned short* __restrict__ Wt) {
    const int h = blockIdx.x;
    const int mat = blockIdx.y;
    const int e = threadIdx.x;
    const float* W = (mat == 0) ? Wq : ((mat == 1) ? Wk : Wv);
    Wt[(mat * 64 + h) * 512 + e] = nbfu(W[e * 64 + h]);
}

// Fused QKV projection v3: async LDS staging (global_load_lds w16, double
// buffered) for BOTH A (x1, fp32, XOR-swizzled) and B (Wt, fragment-ordered
// layout [n][c][g] -> conflict-free ds_read_b128 + 64B-contiguous L2 source).
// Per k-step: 5 GLDS16/thread, 2+12 ds_read_b128/lane, 12 MFMA/wave.
__global__ __launch_bounds__(256, 2) void qkv_proj(
    const float* __restrict__ x1, const unsigned short* __restrict__ Wt,
    unsigned short* __restrict__ Q, unsigned short* __restrict__ K,
    unsigned short* __restrict__ Vt)
{
    __shared__ char alds[2][8192];    // A tile: 64 tok x 32 e fp32 (swizzled)
    __shared__ char blds[2][12288];   // B tile: [n=12][c=16][g=4] 16B frags

    const int tid = threadIdx.x;
    const int w = tid >> 6, lane = tid & 63;
    const int c = lane & 15, g = lane >> 4;
    const int tokB = blockIdx.x * 64;

    const char* x1b = (const char*)x1;
    const char* Wtb = (const char*)Wt;

    // A staging source (chunks j=tid, tid+256): tok=j>>3, phys slot qp=j&7,
    // logical q = qp ^ (tok&7)  [st-style XOR swizzle]
    const int tA0 = tid >> 3,           qA0 = (tid & 7) ^ (tA0 & 7);
    const int tA1 = (tid + 256) >> 3,   qA1 = (tid & 7) ^ (tA1 & 7);
    const size_t aoff0 = (size_t)(tokB + tA0) * 2048 + qA0 * 16;
    const size_t aoff1 = (size_t)(tokB + tA1) * 2048 + qA1 * 16;

    // B staging source (chunks j=tid, +256, +512): j=(n,c2,g2)=(j>>6,(j>>2)&15,j&3)
    // source row hh = (n>>2)*64 + (n&3)*16 + c2 (1024B rows), byte g2*16 within k-slab
    auto bsrc = [&](int j) -> size_t {
        const int n = j >> 6, c2 = (j >> 2) & 15, g2 = j & 3;
        return (size_t)((n >> 2) * 64 + (n & 3) * 16 + c2) * 1024 + g2 * 16;
    };
    const size_t boff0 = bsrc(tid), boff1 = bsrc(tid + 256), boff2 = bsrc(tid + 512);

    f32x4 acc[12];
#pragma unroll
    for (int n = 0; n < 12; ++n) acc[n] = (f32x4)0.f;

    // prologue: stage ks=0 into buf 0
    GLDS16(x1b + aoff0, &alds[0][tid * 16]);
    GLDS16(x1b + aoff1, &alds[0][4096 + tid * 16]);
    GLDS16(Wtb + boff0, &blds[0][tid * 16]);
    GLDS16(Wtb + boff1, &blds[0][4096 + tid * 16]);
    GLDS16(Wtb + boff2, &blds[0][8192 + tid * 16]);

    const int arow = (w * 16 + c) * 128;
    const int aq0 = (((2 * g) ^ (c & 7)) * 16);
    const int aq1 = (((2 * g + 1) ^ (c & 7)) * 16);
    const int brd = (c * 4 + g) * 16;

    int buf = 0;
    for (int ks = 0; ks < 16; ++ks) {
        asm volatile("s_waitcnt vmcnt(0)\n\ts_barrier" ::: "memory");

        if (ks < 15) {
            const size_t ka = (size_t)(ks + 1) * 128;
            const size_t kb = (size_t)(ks + 1) * 64;
            char* ab = &alds[buf ^ 1][0];
            char* bb = &blds[buf ^ 1][0];
            GLDS16(x1b + aoff0 + ka, ab + tid * 16);
            GLDS16(x1b + aoff1 + ka, ab + 4096 + tid * 16);
            GLDS16(Wtb + boff0 + kb, bb + tid * 16);
            GLDS16(Wtb + boff1 + kb, bb + 4096 + tid * 16);
            GLDS16(Wtb + boff2 + kb, bb + 8192 + tid * 16);
        }

        const char* ab = &alds[buf][0];
        const char* bb = &blds[buf][0];
        f32x4 a0 = *(const f32x4*)(ab + arow + aq0);
        f32x4 a1 = *(const f32x4*)(ab + arow + aq1);
        bf16x8 af;
        af[0] = nbf(a0[0]); af[1] = nbf(a0[1]); af[2] = nbf(a0[2]); af[3] = nbf(a0[3]);
        af[4] = nbf(a1[0]); af[5] = nbf(a1[1]); af[6] = nbf(a1[2]); af[7] = nbf(a1[3]);
#pragma unroll
        for (int n = 0; n < 12; ++n) {
            bf16x8 bf = *(const bf16x8*)(bb + n * 1024 + brd);
            acc[n] = MFMA16(af, bf, acc[n]);
        }

        asm volatile("s_waitcnt lgkmcnt(0)\n\ts_barrier" ::: "memory");
        buf ^= 1;
    }

    const int tok0 = tokB + w * 16;
#pragma unroll
    for (int n = 0; n < 4; ++n)
#pragma unroll
        for (int r = 0; r < 4; ++r)
            Q[(size_t)(tok0 + g * 4 + r) * 64 + n * 16 + c] = nbfu(acc[n][r] * QSCALE);
#pragma unroll
    for (int n = 0; n < 4; ++n)
#pragma unroll
        for (int r = 0; r < 4; ++r)
            K[(size_t)(tok0 + g * 4 + r) * 64 + n * 16 + c] = nbfu(acc[4 + n][r]);

    const int b = tok0 >> 11;
    const int sl = (tok0 & 2047) + g * 4;
#pragma unroll
    for (int n = 0; n < 4; ++n) {
        const int d = n * 16 + c;
        u16x4 pv;
#pragma unroll
        for (int r = 0; r < 4; ++r) pv[r] = nbfu(acc[8 + n][r]);
        *(u16x4*)(Vt + ((size_t)(b * 64 + d) << 11) + sl) = pv;
    }
}

// Causal flash attention v3 (unchanged structure from R3; native cvt in P path).
__global__ __launch_bounds__(256, 1) void flash_attn(
    const unsigned short* __restrict__ Q, const unsigned short* __restrict__ K,
    const unsigned short* __restrict__ Vt, float* __restrict__ out)
{
    __shared__ unsigned short kv[2][8192];      // [buf][ K:0..4095 | V:4096..8191 ]
    __shared__ unsigned short p_lds[4][16][72];

    const int w = threadIdx.x >> 6;
    const int lane = threadIdx.x & 63;
    const int c = lane & 15, g = lane >> 4;

    const int id = blockIdx.x;
    const int xcd = id & 7;
    const int b = 2 * xcd + ((id >> 3) & 1);    // per-XCD batch pair -> L2-resident K/V
    const int bxx = id >> 4;
    const int qt = (bxx < 16) ? bxx : 47 - bxx; // CU pair (id,id+256): qt sum = 31
    const int qr0 = qt * 64 + w * 16;
    const size_t qrow_g = ((size_t)b << 11) + qr0;

    bf16x8 qf0 = *(const bf16x8*)(Q + (qrow_g + c) * 64 + g * 8);
    bf16x8 qf1 = *(const bf16x8*)(Q + (qrow_g + c) * 64 + 32 + g * 8);

    const char* Kb = (const char*)(K + (((size_t)b << 11) * 64));
    const char* Vb = (const char*)(Vt + (((size_t)b << 11) * 64));   // [d=64][s=2048]

    const int j0 = w * 64 + lane;
    const int j1 = (w + 4) * 64 + lane;
    const int sw0 = (((j0 & 7) << 4) ^ (((j0 >> 3) & 7) << 4));
    const int sw1 = (((j1 & 7) << 4) ^ (((j1 >> 3) & 7) << 4));
    const int offk0 = (j0 >> 3) * 128 + sw0;
    const int offk1 = (j1 >> 3) * 128 + sw1;
    const int offv0 = (j0 >> 3) * 4096 + sw0;
    const int offv1 = (j1 >> 3) * 4096 + sw1;

    float m_run = -1e30f, l_run = 0.f;
    f32x4 acc_o[4];
#pragma unroll
    for (int n = 0; n < 4; ++n) acc_o[n] = (f32x4)0.f;

    int buf = 0;
    {
        GLDS16(Kb + offk0, &kv[0][w * 512]);
        GLDS16(Kb + offk1, &kv[0][(w + 4) * 512]);
        GLDS16(Vb + offv0, &kv[0][4096 + w * 512]);
        GLDS16(Vb + offv1, &kv[0][4096 + (w + 4) * 512]);
    }

    const int sx = (c & 7) << 4;

    for (int kt = 0; kt <= qt; ++kt) {
        asm volatile("s_waitcnt vmcnt(0)\n\ts_barrier" ::: "memory");

        if (kt < qt) {
            const size_t ko = (size_t)(kt + 1) * 8192;
            const size_t vo = (size_t)(kt + 1) * 128;
            GLDS16(Kb + ko + offk0, &kv[buf ^ 1][w * 512]);
            GLDS16(Kb + ko + offk1, &kv[buf ^ 1][(w + 4) * 512]);
            GLDS16(Vb + vo + offv0, &kv[buf ^ 1][4096 + w * 512]);
            GLDS16(Vb + vo + offv1, &kv[buf ^ 1][4096 + (w + 4) * 512]);
        }

        const char* klc = (const char*)&kv[buf][0];
        f32x4 s[4];
#pragma unroll
        for (int n = 0; n < 4; ++n) s[n] = (f32x4)0.f;
        __builtin_amdgcn_s_setprio(1);
#pragma unroll
        for (int n = 0; n < 4; ++n) {
            const int ro = (n * 16 + c) * 128;
            bf16x8 ka = *(const bf16x8*)(klc + ro + ((g * 16) ^ sx));
            bf16x8 kb2 = *(const bf16x8*)(klc + ro + ((64 + g * 16) ^ sx));
            s[n] = MFMA16(ka, qf0, s[n]);
            s[n] = MFMA16(kb2, qf1, s[n]);
        }
        __builtin_amdgcn_s_setprio(0);

        if (kt == qt) {
#pragma unroll
            for (int n = 0; n < 4; ++n) {
                const int key = kt * 64 + n * 16 + g * 4;
#pragma unroll
                for (int r = 0; r < 4; ++r)
                    if (key + r > qr0 + c) s[n][r] = -1e30f;
            }
        }

        float tm = s[0][0];
#pragma unroll
        for (int n = 0; n < 4; ++n)
#pragma unroll
            for (int r = 0; r < 4; ++r) tm = fmaxf(tm, s[n][r]);
        tm = fmaxf(tm, __shfl_xor(tm, 16, 64));
        tm = fmaxf(tm, __shfl_xor(tm, 32, 64));

        if (__any(tm > m_run + 8.f)) {
            const float mn = fmaxf(m_run, tm);
            const float alpha = exp2f(m_run - mn);
            m_run = mn;
            l_run *= alpha;
            float al[4];
#pragma unroll
            for (int r = 0; r < 4; ++r) al[r] = __shfl(alpha, g * 4 + r, 16);
#pragma unroll
            for (int n = 0; n < 4; ++n)
#pragma unroll
                for (int r = 0; r < 4; ++r) acc_o[n][r] *= al[r];
        }

        float rs = 0.f;
#pragma unroll
        for (int n = 0; n < 4; ++n) {
            u16x4 pk;
#pragma unroll
            for (int r = 0; r < 4; ++r) {
                const float p = exp2f(s[n][r] - m_run);
                rs += p;
                pk[r] = nbfu(p);
            }
            *(u16x4*)&p_lds[w][c][n * 16 + g * 4] = pk;
        }
        rs += __shfl_xor(rs, 16, 64);
        rs += __shfl_xor(rs, 32, 64);
        l_run += rs;

        bf16x8 pf0 = *(const bf16x8*)&p_lds[w][c][g * 8];
        bf16x8 pf1 = *(const bf16x8*)&p_lds[w][c][32 + g * 8];
        const char* vlc = (const char*)&kv[buf][4096];
        __builtin_amdgcn_s_setprio(1);
#pragma unroll
        for (int n = 0; n < 4; ++n) {
            const int ro = (n * 16 + c) * 128;
            bf16x8 va = *(const bf16x8*)(vlc + ro + ((g * 16) ^ sx));
            bf16x8 vb2 = *(const bf16x8*)(vlc + ro + ((64 + g * 16) ^ sx));
            acc_o[n] = MFMA16(pf0, va, acc_o[n]);
            acc_o[n] = MFMA16(pf1, vb2, acc_o[n]);
        }
        __builtin_amdgcn_s_setprio(0);

        asm volatile("s_waitcnt lgkmcnt(0)\n\ts_barrier" ::: "memory");
        buf ^= 1;
    }

    const float inv_l = 1.f / l_run;
    float il[4];
#pragma unroll
    for (int r = 0; r < 4; ++r) il[r] = __shfl(inv_l, g * 4 + r, 16);
#pragma unroll
    for (int n = 0; n < 4; ++n)
#pragma unroll
        for (int r = 0; r < 4; ++r)
            out[(qrow_g + g * 4 + r) * 64 + n * 16 + c] = acc_o[n][r] * il[r];
}

extern "C" void kernel_launch(void* const* d_in, const int* in_sizes, int n_in,
                              void* d_out, int out_size, void* d_ws, size_t ws_size,
                              hipStream_t stream) {
    const float* x1 = (const float*)d_in[0];
    const float* Wq = (const float*)d_in[2];
    const float* Wk = (const float*)d_in[3];
    const float* Wv = (const float*)d_in[4];
    float* out = (float*)d_out;

    unsigned short* Wt  = (unsigned short*)d_ws;
    unsigned short* Qw  = (unsigned short*)((char*)d_ws + 196608);
    unsigned short* Kw  = (unsigned short*)((char*)d_ws + 196608 + 4194304);
    unsigned short* Vtw = (unsigned short*)((char*)d_ws + 196608 + 2 * 4194304);

    wt_kernel<<<dim3(64, 3), 512, 0, stream>>>(Wq, Wk, Wv, Wt);
    qkv_proj<<<512, 256, 0, stream>>>(x1, Wt, Qw, Kw, Vtw);
    flash_attn<<<512, 256, 0, stream>>>(Qw, Kw, Vtw, out);
}

// Round 5
// 72.593 us; speedup vs baseline: 2.5740x; 1.0277x over previous
//
#include <hip/hip_runtime.h>
#include <hip/hip_bf16.h>

typedef __attribute__((ext_vector_type(8))) short bf16x8;
typedef __attribute__((ext_vector_type(4))) float f32x4;
typedef __attribute__((ext_vector_type(4))) unsigned short u16x4;

#define MFMA16(a, b, c) __builtin_amdgcn_mfma_f32_16x16x32_bf16(a, b, c, 0, 0, 0)

// B=16, S=2048, EMB=512, HEAD_DIM=64
// Q pre-scaled by 0.125 * log2(e): softmax runs in exp2 domain.
#define QSCALE 0.18033688011112042f

#define GLDS16(gp, lp)                                                         \
    __builtin_amdgcn_global_load_lds(                                          \
        (const __attribute__((address_space(1))) void*)(gp),                   \
        (__attribute__((address_space(3))) void*)(lp), 16, 0, 0)

__device__ __forceinline__ short nbf(float f) {
    __hip_bfloat16 h = __float2bfloat16(f);
    return *(short*)&h;
}
__device__ __forceinline__ unsigned short nbfu(float f) {
    __hip_bfloat16 h = __float2bfloat16(f);
    return *(unsigned short*)&h;
}

// Wt[mat][h][e] = bf16(W_mat[e][h])
__global__ void wt_kernel(const float* __restrict__ Wq, const float* __restrict__ Wk,
                          const float* __restrict__ Wv, unsigned short* __restrict__ Wt) {
    const int h = blockIdx.x;
    const int mat = blockIdx.y;
    const int e = threadIdx.x;
    const float* W = (mat == 0) ? Wq : ((mat == 1) ? Wk : Wv);
    Wt[(mat * 64 + h) * 512 + e] = nbfu(W[e * 64 + h]);
}

// Fused QKV projection (R4 structure; single barrier per k-step).
__global__ __launch_bounds__(256, 2) void qkv_proj(
    const float* __restrict__ x1, const unsigned short* __restrict__ Wt,
    unsigned short* __restrict__ Q, unsigned short* __restrict__ K,
    unsigned short* __restrict__ Vt)
{
    __shared__ char alds[2][8192];    // A tile: 64 tok x 32 e fp32 (swizzled)
    __shared__ char blds[2][12288];   // B tile: [n=12][c=16][g=4] 16B frags

    const int tid = threadIdx.x;
    const int w = tid >> 6, lane = tid & 63;
    const int c = lane & 15, g = lane >> 4;
    const int tokB = blockIdx.x * 64;

    const char* x1b = (const char*)x1;
    const char* Wtb = (const char*)Wt;

    const int tA0 = tid >> 3,           qA0 = (tid & 7) ^ (tA0 & 7);
    const int tA1 = (tid + 256) >> 3,   qA1 = (tid & 7) ^ (tA1 & 7);
    const size_t aoff0 = (size_t)(tokB + tA0) * 2048 + qA0 * 16;
    const size_t aoff1 = (size_t)(tokB + tA1) * 2048 + qA1 * 16;

    auto bsrc = [&](int j) -> size_t {
        const int n = j >> 6, c2 = (j >> 2) & 15, g2 = j & 3;
        return (size_t)((n >> 2) * 64 + (n & 3) * 16 + c2) * 1024 + g2 * 16;
    };
    const size_t boff0 = bsrc(tid), boff1 = bsrc(tid + 256), boff2 = bsrc(tid + 512);

    f32x4 acc[12];
#pragma unroll
    for (int n = 0; n < 12; ++n) acc[n] = (f32x4)0.f;

    GLDS16(x1b + aoff0, &alds[0][tid * 16]);
    GLDS16(x1b + aoff1, &alds[0][4096 + tid * 16]);
    GLDS16(Wtb + boff0, &blds[0][tid * 16]);
    GLDS16(Wtb + boff1, &blds[0][4096 + tid * 16]);
    GLDS16(Wtb + boff2, &blds[0][8192 + tid * 16]);

    const int arow = (w * 16 + c) * 128;
    const int aq0 = (((2 * g) ^ (c & 7)) * 16);
    const int aq1 = (((2 * g + 1) ^ (c & 7)) * 16);
    const int brd = (c * 4 + g) * 16;

    int buf = 0;
    for (int ks = 0; ks < 16; ++ks) {
        asm volatile("s_waitcnt vmcnt(0)\n\ts_barrier" ::: "memory");

        if (ks < 15) {
            const size_t ka = (size_t)(ks + 1) * 128;
            const size_t kb = (size_t)(ks + 1) * 64;
            char* ab = &alds[buf ^ 1][0];
            char* bb = &blds[buf ^ 1][0];
            GLDS16(x1b + aoff0 + ka, ab + tid * 16);
            GLDS16(x1b + aoff1 + ka, ab + 4096 + tid * 16);
            GLDS16(Wtb + boff0 + kb, bb + tid * 16);
            GLDS16(Wtb + boff1 + kb, bb + 4096 + tid * 16);
            GLDS16(Wtb + boff2 + kb, bb + 8192 + tid * 16);
        }

        const char* ab = &alds[buf][0];
        const char* bb = &blds[buf][0];
        f32x4 a0 = *(const f32x4*)(ab + arow + aq0);
        f32x4 a1 = *(const f32x4*)(ab + arow + aq1);
        bf16x8 af;
        af[0] = nbf(a0[0]); af[1] = nbf(a0[1]); af[2] = nbf(a0[2]); af[3] = nbf(a0[3]);
        af[4] = nbf(a1[0]); af[5] = nbf(a1[1]); af[6] = nbf(a1[2]); af[7] = nbf(a1[3]);
#pragma unroll
        for (int n = 0; n < 12; ++n) {
            bf16x8 bf = *(const bf16x8*)(bb + n * 1024 + brd);
            acc[n] = MFMA16(af, bf, acc[n]);
        }
        // no bottom barrier needed: ds_reads above are consumed by the MFMAs
        // before any wave reaches the next top barrier; GLDS writes only touch buf^1.
        buf ^= 1;
    }

    const int tok0 = tokB + w * 16;
#pragma unroll
    for (int n = 0; n < 4; ++n)
#pragma unroll
        for (int r = 0; r < 4; ++r)
            Q[(size_t)(tok0 + g * 4 + r) * 64 + n * 16 + c] = nbfu(acc[n][r] * QSCALE);
#pragma unroll
    for (int n = 0; n < 4; ++n)
#pragma unroll
        for (int r = 0; r < 4; ++r)
            K[(size_t)(tok0 + g * 4 + r) * 64 + n * 16 + c] = nbfu(acc[4 + n][r]);

    const int b = tok0 >> 11;
    const int sl = (tok0 & 2047) + g * 4;
#pragma unroll
    for (int n = 0; n < 4; ++n) {
        const int d = n * 16 + c;
        u16x4 pv;
#pragma unroll
        for (int r = 0; r < 4; ++r) pv[r] = nbfu(acc[8 + n][r]);
        *(u16x4*)(Vt + ((size_t)(b * 64 + d) << 11) + sl) = pv;
    }
}

// Causal flash attention v4:
//  - fragment-ordered K/V LDS layout [slab][n][c][g]x16B -> wave-wide
//    ds_read_b128 hits 64 consecutive slots = conflict-free.
//  - 2 blocks/CU co-residency (launch_bounds(256,2)): paired blocks (id,id+256)
//    same XCD/batch, complementary qt -> mutual latency hiding.
//  - single barrier per iteration; tree-shaped softmax reductions.
__global__ __launch_bounds__(256, 2) void flash_attn(
    const unsigned short* __restrict__ Q, const unsigned short* __restrict__ K,
    const unsigned short* __restrict__ Vt, float* __restrict__ out)
{
    __shared__ unsigned short kv[2][8192];      // [buf][ K:0..4095 | V:4096..8191 ]
    __shared__ unsigned short p_lds[4][16][72];

    const int tid = threadIdx.x;
    const int w = tid >> 6;
    const int lane = tid & 63;
    const int c = lane & 15, g = lane >> 4;

    const int id = blockIdx.x;
    const int xcd = id & 7;
    const int b = 2 * xcd + ((id >> 3) & 1);    // per-XCD batch pair -> L2-resident K/V
    const int bxx = id >> 4;
    const int qt = (bxx < 16) ? bxx : 47 - bxx; // CU pair (id,id+256): qt sum = 31
    const int qr0 = qt * 64 + w * 16;
    const size_t qrow_g = ((size_t)b << 11) + qr0;

    bf16x8 qf0 = *(const bf16x8*)(Q + (qrow_g + c) * 64 + g * 8);
    bf16x8 qf1 = *(const bf16x8*)(Q + (qrow_g + c) * 64 + 32 + g * 8);

    const char* Kb = (const char*)(K + (((size_t)b << 11) * 64));
    const char* Vb = (const char*)(Vt + (((size_t)b << 11) * 64));   // [d=64][s=2048]

    // staging: chunk j = (slab=j>>8, n=(j>>6)&3, c2=(j>>2)&15, g2=j&3);
    // thread tid stages j=tid (slab0) and j=tid+256 (slab1); dest linear j*16.
    const int rowK = (w * 16 + (lane >> 2)) * 128 + (lane & 3) * 16;  // K src, slab0
    const size_t rowV = (size_t)(w * 16 + (lane >> 2)) * 4096 + (lane & 3) * 16;

    float m_run = -1e30f, l_run = 0.f;
    f32x4 acc_o[4];
#pragma unroll
    for (int n = 0; n < 4; ++n) acc_o[n] = (f32x4)0.f;

    int buf = 0;
    {   // prologue: stage tile 0 into buf 0
        GLDS16(Kb + rowK,      &kv[0][tid * 8]);
        GLDS16(Kb + rowK + 64, &kv[0][2048 + tid * 8]);
        GLDS16(Vb + rowV,      &kv[0][4096 + tid * 8]);
        GLDS16(Vb + rowV + 64, &kv[0][4096 + 2048 + tid * 8]);
    }

    const int fo = (c * 4 + g) * 8;   // my fragment slot within a 512-short n-block

    for (int kt = 0; kt <= qt; ++kt) {
        // my 4 GLDS for kv[buf] drained; barrier -> all waves' stages complete,
        // and all waves' reads of kv[buf^1] (consumed by MFMAs) are done.
        asm volatile("s_waitcnt vmcnt(0)\n\ts_barrier" ::: "memory");

        if (kt < qt) {
            const size_t ko = (size_t)(kt + 1) * 8192;
            const size_t vo = (size_t)(kt + 1) * 128;
            unsigned short* kb = &kv[buf ^ 1][0];
            GLDS16(Kb + ko + rowK,      kb + tid * 8);
            GLDS16(Kb + ko + rowK + 64, kb + 2048 + tid * 8);
            GLDS16(Vb + vo + rowV,      kb + 4096 + tid * 8);
            GLDS16(Vb + vo + rowV + 64, kb + 4096 + 2048 + tid * 8);
        }

        // ---- S^T = K Q^T from LDS (conflict-free fragment reads) ----
        const unsigned short* kbuf = &kv[buf][0];
        f32x4 s[4];
#pragma unroll
        for (int n = 0; n < 4; ++n) s[n] = (f32x4)0.f;
        __builtin_amdgcn_s_setprio(1);
#pragma unroll
        for (int n = 0; n < 4; ++n) {
            bf16x8 ka  = *(const bf16x8*)(kbuf + n * 512 + fo);
            bf16x8 kb2 = *(const bf16x8*)(kbuf + 2048 + n * 512 + fo);
            s[n] = MFMA16(ka, qf0, s[n]);
            s[n] = MFMA16(kb2, qf1, s[n]);
        }
        __builtin_amdgcn_s_setprio(0);

        // ---- causal mask (diagonal tile only) ----
        if (kt == qt) {
#pragma unroll
            for (int n = 0; n < 4; ++n) {
                const int key = kt * 64 + n * 16 + g * 4;
#pragma unroll
                for (int r = 0; r < 4; ++r)
                    if (key + r > qr0 + c) s[n][r] = -1e30f;
            }
        }

        // ---- online softmax (exp2 domain, defer-max THR=8), tree reductions ----
        float t0 = fmaxf(fmaxf(s[0][0], s[0][1]), fmaxf(s[0][2], s[0][3]));
        float t1 = fmaxf(fmaxf(s[1][0], s[1][1]), fmaxf(s[1][2], s[1][3]));
        float t2 = fmaxf(fmaxf(s[2][0], s[2][1]), fmaxf(s[2][2], s[2][3]));
        float t3 = fmaxf(fmaxf(s[3][0], s[3][1]), fmaxf(s[3][2], s[3][3]));
        float tm = fmaxf(fmaxf(t0, t1), fmaxf(t2, t3));
        tm = fmaxf(tm, __shfl_xor(tm, 16, 64));
        tm = fmaxf(tm, __shfl_xor(tm, 32, 64));

        if (__any(tm > m_run + 8.f)) {
            const float mn = fmaxf(m_run, tm);
            const float alpha = exp2f(m_run - mn);
            m_run = mn;
            l_run *= alpha;
            float al[4];
#pragma unroll
            for (int r = 0; r < 4; ++r) al[r] = __shfl(alpha, g * 4 + r, 16);
#pragma unroll
            for (int n = 0; n < 4; ++n)
#pragma unroll
                for (int r = 0; r < 4; ++r) acc_o[n][r] *= al[r];
        }

        float rsn[4];
#pragma unroll
        for (int n = 0; n < 4; ++n) {
            u16x4 pk;
            float p0 = exp2f(s[n][0] - m_run);
            float p1 = exp2f(s[n][1] - m_run);
            float p2 = exp2f(s[n][2] - m_run);
            float p3 = exp2f(s[n][3] - m_run);
            pk[0] = nbfu(p0); pk[1] = nbfu(p1); pk[2] = nbfu(p2); pk[3] = nbfu(p3);
            rsn[n] = (p0 + p1) + (p2 + p3);
            *(u16x4*)&p_lds[w][c][n * 16 + g * 4] = pk;
        }
        float rs = (rsn[0] + rsn[1]) + (rsn[2] + rsn[3]);
        rs += __shfl_xor(rs, 16, 64);
        rs += __shfl_xor(rs, 32, 64);
        l_run += rs;

        // ---- O += P V (conflict-free V fragment reads) ----
        bf16x8 pf0 = *(const bf16x8*)&p_lds[w][c][g * 8];
        bf16x8 pf1 = *(const bf16x8*)&p_lds[w][c][32 + g * 8];
        const unsigned short* vbuf = &kv[buf][4096];
        __builtin_amdgcn_s_setprio(1);
#pragma unroll
        for (int n = 0; n < 4; ++n) {
            bf16x8 va  = *(const bf16x8*)(vbuf + n * 512 + fo);
            bf16x8 vb2 = *(const bf16x8*)(vbuf + 2048 + n * 512 + fo);
            acc_o[n] = MFMA16(pf0, va, acc_o[n]);
            acc_o[n] = MFMA16(pf1, vb2, acc_o[n]);
        }
        __builtin_amdgcn_s_setprio(0);

        buf ^= 1;
    }

    const float inv_l = 1.f / l_run;
    float il[4];
#pragma unroll
    for (int r = 0; r < 4; ++r) il[r] = __shfl(inv_l, g * 4 + r, 16);
#pragma unroll
    for (int n = 0; n < 4; ++n)
#pragma unroll
        for (int r = 0; r < 4; ++r)
            out[(qrow_g + g * 4 + r) * 64 + n * 16 + c] = acc_o[n][r] * il[r];
}

extern "C" void kernel_launch(void* const* d_in, const int* in_sizes, int n_in,
                              void* d_out, int out_size, void* d_ws, size_t ws_size,
                              hipStream_t stream) {
    const float* x1 = (const float*)d_in[0];
    const float* Wq = (const float*)d_in[2];
    const float* Wk = (const float*)d_in[3];
    const float* Wv = (const float*)d_in[4];
    float* out = (float*)d_out;

    unsigned short* Wt  = (unsigned short*)d_ws;
    unsigned short* Qw  = (unsigned short*)((char*)d_ws + 196608);
    unsigned short* Kw  = (unsigned short*)((char*)d_ws + 196608 + 4194304);
    unsigned short* Vtw = (unsigned short*)((char*)d_ws + 196608 + 2 * 4194304);

    wt_kernel<<<dim3(64, 3), 512, 0, stream>>>(Wq, Wk, Wv, Wt);
    qkv_proj<<<512, 256, 0, stream>>>(x1, Wt, Qw, Kw, Vtw);
    flash_attn<<<512, 256, 0, stream>>>(Qw, Kw, Vtw, out);
}